// Round 1
// 370.175 us; speedup vs baseline: 1.0344x; 1.0344x over previous
//
#include <hip/hip_runtime.h>

// Problem constants (from reference)
#define BATCH   64
#define CH      3
#define H_OUT   608
#define W_OUT   608
#define H_IN    416
#define W_IN    416
#define ROW_OFF 85
#define COL_OFF 80

#define W4_OUT  (W_OUT / 4)          // 152 float4 per output row
#define W4_IN   (W_IN / 4)           // 104 float4 per input row
#define PLANE4  (H_OUT * W4_OUT)     // 92416 float4 per (b,c) output plane
#define IPLANE4 (H_IN * W4_IN)       // 43264 float4 per (b,c) input plane

#define BCHUNK  4                    // batches per thread

// native vector type: __builtin_nontemporal_{load,store} requires a
// scalar/vector type, not HIP's float4 struct
typedef float v4f __attribute__((ext_vector_type(4)));

#define SEL(o, m, v, r) \
    o.x = (m.x != 0.0f) ? v.x : r.x; \
    o.y = (m.y != 0.0f) ? v.y : r.y; \
    o.z = (m.z != 0.0f) ? v.z : r.z; \
    o.w = (m.w != 0.0f) ? v.w : r.w;

__global__ __launch_bounds__(256)
void composite_kernel(const v4f* __restrict__ img,
                      const v4f* __restrict__ ref,
                      v4f* __restrict__ out)
{
    const int i  = blockIdx.x * 256 + threadIdx.x;  // float4 position in plane
    const int b0 = blockIdx.y * BCHUNK;

    const int y  = i / W4_OUT;            // magic-mul division (const divisor)
    const int x4 = i - y * W4_OUT;

    // ref is reused 16x across the grid -> keep it cacheable (plain loads)
    const v4f r0 = ref[0 * PLANE4 + i];
    const v4f r1 = ref[1 * PLANE4 + i];
    const v4f r2 = ref[2 * PLANE4 + i];

    const int yy = y - ROW_OFF;
    const int xx = x4 * 4 - COL_OFF;      // multiple of 4 inside window
    const bool inw = (yy >= 0 && yy < H_IN && xx >= 0 && xx < W_IN);

    if (inw) {
        const int base = yy * W4_IN + (xx >> 2);

        // Phase 1: issue ALL 12 loads before any consumer -> 12 outstanding
        // global_load_dwordx4 per thread (MLP), instead of ~3 when
        // load/select/store are interleaved per batch.
        // img is read exactly once -> nontemporal (don't pollute L2).
        v4f v0[BCHUNK], v1[BCHUNK], vm[BCHUNK];
        #pragma unroll
        for (int j = 0; j < BCHUNK; ++j) {
            const int b = b0 + j;
            v0[j] = __builtin_nontemporal_load(&img[(b * CH + 0) * IPLANE4 + base]);
            v1[j] = __builtin_nontemporal_load(&img[(b * CH + 1) * IPLANE4 + base]);
            vm[j] = __builtin_nontemporal_load(&img[(b * CH + 2) * IPLANE4 + base]);
        }

        // Phase 2: select + store. out is write-once, never re-read ->
        // nontemporal stores (stream past L2).
        #pragma unroll
        for (int j = 0; j < BCHUNK; ++j) {
            const int b = b0 + j;
            v4f o0, o1, o2;
            SEL(o0, vm[j], v0[j], r0)
            SEL(o1, vm[j], v1[j], r1)
            SEL(o2, vm[j], vm[j], r2)
            __builtin_nontemporal_store(o0, &out[(b * CH + 0) * PLANE4 + i]);
            __builtin_nontemporal_store(o1, &out[(b * CH + 1) * PLANE4 + i]);
            __builtin_nontemporal_store(o2, &out[(b * CH + 2) * PLANE4 + i]);
        }
    } else {
        #pragma unroll
        for (int j = 0; j < BCHUNK; ++j) {
            const int b = b0 + j;
            __builtin_nontemporal_store(r0, &out[(b * CH + 0) * PLANE4 + i]);
            __builtin_nontemporal_store(r1, &out[(b * CH + 1) * PLANE4 + i]);
            __builtin_nontemporal_store(r2, &out[(b * CH + 2) * PLANE4 + i]);
        }
    }
}

extern "C" void kernel_launch(void* const* d_in, const int* in_sizes, int n_in,
                              void* d_out, int out_size, void* d_ws, size_t ws_size,
                              hipStream_t stream) {
    const v4f* img = (const v4f*)d_in[0];   // [64,3,416,416] f32
    const v4f* ref = (const v4f*)d_in[1];   // [1,3,608,608] f32
    v4f* out = (v4f*)d_out;                 // [64,3,608,608] f32

    dim3 grid(PLANE4 / 256, BATCH / BCHUNK);      // (361, 16)
    composite_kernel<<<grid, 256, 0, stream>>>(img, ref, out);
}